// Round 11
// baseline (901.779 us; speedup 1.0000x reference)
//
#include <hip/hip_runtime.h>
#include <hip/hip_bf16.h>

// Problem: T=512, B=64, N=256, H=64, D=128, P=64.
// Stage 1: x2n = input(32768x128) @ W2n^T(128x256) + b2n          (gemm_xwT)
// Stage 2: 16384 independent LSTM cells scanned over 512 steps    (lstm_scan)
// Stage 3: out = ON(32768x256) @ Wout^T(256x64) + bout            (gemm_xwT)
// Workspace: x2n 32MB + ON 32MB = 64MB of d_ws.
//
// Scan (round-11) = R7 structure (best measured: 866us) + two fixes:
//   - amdgpu_waves_per_eu(1,1): R6-R10 all showed VGPR_Count 136-200 with
//     the 128-VGPR weight set rematerialized from L1/L2 every step (hidden
//     from FETCH_SIZE, visible as the ~570cyc/step stall).  launch_bounds'
//     2nd arg is only a MIN; the allocator still targeted high occupancy.
//     Capping max waves/EU at 1 gives it the full 512-reg budget.
//   - f32 register init replaces the 16 ext-slice MFMAs: acc[nt][e] =
//     fma(x, wiv[nt][e], biv[nt][e]) with wiv/biv f32-resident (128 VGPRs,
//     affordable at 512 budget).  MFMA/step 48->32, no divergent bx8 build,
//     no xh/xl split, exact f32 x-path (better precision than bf16-split).
// Keeps: K=32 MFMA, R7 block ordering (init, ks0 sweep, ks1 sweep, NL by
// qp-pairs), merged-rcp NL, packed cvt h->bf16, deferred 2-step g-reduce.

typedef __attribute__((ext_vector_type(4))) float f32x4;
typedef __attribute__((ext_vector_type(4))) short s16x4;
typedef __attribute__((ext_vector_type(8))) short s16x8;
typedef __attribute__((ext_vector_type(4))) unsigned u32x4;

__device__ inline short bf16r(float f) {            // round-to-nearest-even bf16
    unsigned u = __builtin_bit_cast(unsigned, f);
    u += 0x7fffu + ((u >> 16) & 1u);
    return (short)(u >> 16);
}
__device__ inline unsigned pkbf(float a, float b) { // (bf16(a) | bf16(b)<<16), RNE
    unsigned r;
    asm("v_cvt_pk_bf16_f32 %0, %1, %2" : "=v"(r) : "v"(a), "v"(b));
    return r;
}
__device__ inline f32x4 mfma32(s16x8 a, s16x8 b, f32x4 c) {
    return __builtin_amdgcn_mfma_f32_16x16x32_bf16(a, b, c, 0, 0, 0);
}

// ---------------------------------------------------------------------------
// Generic fp32 GEMM: Out(MxN) = X(MxK) @ Wt(NxK)^T + bias(N).  M%64==0,
// N%64==0, K%32==0.  grid = (M/64, N/64), block = 256.
// ---------------------------------------------------------------------------
__global__ __launch_bounds__(256) void gemm_xwT(
    const float* __restrict__ X, const float* __restrict__ Wt,
    const float* __restrict__ bias, float* __restrict__ Out,
    int N, int K)
{
    __shared__ float Xs[32][68];
    __shared__ float Ws[32][68];
    const int tid = threadIdx.x;
    const int tx = tid & 15, ty = tid >> 4;
    const int m0 = blockIdx.x * 64, n0 = blockIdx.y * 64;
    const int kq = tid & 7, mr = tid >> 3;

    float acc[4][4];
#pragma unroll
    for (int i = 0; i < 4; ++i)
#pragma unroll
        for (int j = 0; j < 4; ++j) acc[i][j] = 0.f;

    for (int kc = 0; kc < K; kc += 32) {
#pragma unroll
        for (int rr = 0; rr < 2; ++rr) {
            const int m = mr + rr * 32;
            f32x4 xv = *(const f32x4*)(X + (size_t)(m0 + m) * K + kc + kq * 4);
            f32x4 wv = *(const f32x4*)(Wt + (size_t)(n0 + m) * K + kc + kq * 4);
#pragma unroll
            for (int j = 0; j < 4; ++j) { Xs[kq*4 + j][m] = xv[j]; Ws[kq*4 + j][m] = wv[j]; }
        }
        __syncthreads();
#pragma unroll
        for (int k = 0; k < 32; ++k) {
            f32x4 a = *(const f32x4*)&Xs[k][ty * 4];
            f32x4 b = *(const f32x4*)&Ws[k][tx * 4];
#pragma unroll
            for (int i = 0; i < 4; ++i)
#pragma unroll
                for (int j = 0; j < 4; ++j)
                    acc[i][j] = __builtin_fmaf(a[i], b[j], acc[i][j]);
        }
        __syncthreads();
    }
    f32x4 bv = *(const f32x4*)(bias + n0 + tx * 4);
#pragma unroll
    for (int i = 0; i < 4; ++i) {
        f32x4 o;
#pragma unroll
        for (int j = 0; j < 4; ++j) o[j] = acc[i][j] + bv[j];
        *(f32x4*)(Out + (size_t)(m0 + ty * 4 + i) * N + n0 + tx * 4) = o;
    }
}

// ---------------------------------------------------------------------------
// Recurrent scan, register-only h.  1024 blocks x 64 threads; each wave owns
// 16 cells (cell = cellbase + (lane&15)) for all 512 steps; 1 wave/SIMD,
// max-1-wave/EU register budget (512 VGPRs).
//
// MFMA 16x16x32 bf16 layouts, lane l, c15=l&15, g4=l>>4:
//   A: lane elems 0-3 hold A[c15][kbase + 4*g4 + e], elems 4-7: +16
//   B: lane elems 0-3 hold B[kbase + 4*g4 + e][c15], elems 4-7: +16
//   D: lane reg e holds D[4*g4 + e][c15]
//
// Tile nt = type*4 + q (type 0..3 = i,f,g,o).  Lane (g4,c15) elem e of tile
// nt = PRE-SCALED gate nt*16+4g4+e of cell c15; scale -log2e for i/f/o rows,
// +2log2e for g rows.  acc init = sc*(x*w_ih + bias) in exact f32 from
// register-resident wiv/biv.
// ---------------------------------------------------------------------------
__global__
__attribute__((amdgpu_flat_work_group_size(64, 64)))
__attribute__((amdgpu_waves_per_eu(1, 1)))
void lstm_scan(
    const float* __restrict__ x2n,   // [512][16384]
    const float* __restrict__ W_hh,  // [256][64]
    const float* __restrict__ w_ih,  // [256]
    const float* __restrict__ b_ih,  // [256]
    const float* __restrict__ b_hh,  // [256]
    const float* __restrict__ wg,    // [64]
    const float* __restrict__ bg,    // [1]
    float* __restrict__ ON)          // [512][16384]
{
    const int lane = threadIdx.x & 63;
    const int c15 = lane & 15, g4 = lane >> 4;
    const int cellbase = blockIdx.x * 16;
    const float L2E = 1.4426950408889634f;

    // W_hh A-fragments (K=32 pairs), PRE-SCALED, register-resident.
    s16x8 afw8[2][16];
    // w_ih / bias for the f32 init, PRE-SCALED, register-resident:
    // wiv[nt][e] = sc * w_ih[nt*16 + 4*g4 + e], biv likewise.
    f32x4 wiv[16], biv[16];
#pragma unroll
    for (int nt = 0; nt < 16; ++nt) {
        const float sc = ((nt >> 2) == 2) ? (2.f * L2E) : (-L2E);
        const float* wrow = W_hh + (size_t)(nt * 16 + c15) * 64;
#pragma unroll
        for (int kp = 0; kp < 2; ++kp) {
            s16x8 v;
#pragma unroll
            for (int half = 0; half < 2; ++half) {
                f32x4 w = *(const f32x4*)(wrow + (kp * 2 + half) * 16 + g4 * 4);
#pragma unroll
                for (int e = 0; e < 4; ++e) v[half * 4 + e] = bf16r(w[e] * sc);
            }
            afw8[kp][nt] = v;
        }
        const f32x4 wi4 = *(const f32x4*)(w_ih + nt * 16 + g4 * 4);
        const f32x4 bi4 = *(const f32x4*)(b_ih + nt * 16 + g4 * 4);
        const f32x4 bh4 = *(const f32x4*)(b_hh + nt * 16 + g4 * 4);
        f32x4 wv, bv;
#pragma unroll
        for (int e = 0; e < 4; ++e) {
            wv[e] = wi4[e] * sc;
            bv[e] = (bi4[e] + bh4[e]) * sc;
        }
        wiv[nt] = wv;
        biv[nt] = bv;
    }
    // One-time pins (belt-and-suspenders; with waves_per_eu(1,1) the
    // allocator has the full 512-reg budget and no remat incentive).
#pragma unroll
    for (int nt = 0; nt < 16; ++nt) {
        asm volatile("" : "+v"(afw8[0][nt]));
        asm volatile("" : "+v"(afw8[1][nt]));
        asm volatile("" : "+v"(wiv[nt]));
        asm volatile("" : "+v"(biv[nt]));
    }

    // wg, laid out to match hvf: wg_l[q][e] = wg[q*16 + 4*g4 + e]
    f32x4 wg_l[4];
#pragma unroll
    for (int q = 0; q < 4; ++q) wg_l[q] = *(const f32x4*)(wg + q * 16 + g4 * 4);
    const float bg0 = bg[0];

    f32x4 cst[4];
#pragma unroll
    for (int q = 0; q < 4; ++q) cst[q] = (f32x4){0.f, 0.f, 0.f, 0.f};
    s16x8 bh01 = (s16x8){0, 0, 0, 0, 0, 0, 0, 0};   // h k=0..31  B-fragment
    s16x8 bh23 = (s16x8){0, 0, 0, 0, 0, 0, 0, 0};   // h k=32..63 B-fragment

    float g_s1 = 0.f;      // xor16-reduced g-partial of step t-1
    float g2save = 0.f;    // fully-reduced g of step t-2
    float sp0 = 0.f;

    const size_t cellidx = (size_t)cellbase + c15;
    float xs0 = x2n[cellidx];                        // x(t)
    float xs1 = x2n[(size_t)16384 + cellidx];        // x(t+1)

    for (int t = 0; t < 512; ++t) {
        // finish step t-1's g-reduction (independent of everything below)
        const float s2new = g_s1 + __shfl_xor(g_s1, 32, 64);

        // x for this step; prefetch t+2 (full-step HBM latency margin)
        const float xs_cur = xs0;
        xs0 = xs1;
        xs1 = x2n[(size_t)((t + 2) & 511) * 16384 + cellidx];

        // gates^T: exact f32 (x*w+b) init, then two K=32 slices of W_hh@h^T
        f32x4 acc[16];
#pragma unroll
        for (int nt = 0; nt < 16; ++nt) {
            f32x4 c0;
#pragma unroll
            for (int e = 0; e < 4; ++e)
                c0[e] = __builtin_fmaf(xs_cur, wiv[nt][e], biv[nt][e]);
            acc[nt] = c0;
        }
#pragma unroll
        for (int nt = 0; nt < 16; ++nt) acc[nt] = mfma32(afw8[0][nt], bh01, acc[nt]);
#pragma unroll
        for (int nt = 0; nt < 16; ++nt) acc[nt] = mfma32(afw8[1][nt], bh23, acc[nt]);

        // ---- merged nonlinearities (rcp-paired across qa/qb) ----
        f32x4 hvf[4];
#pragma unroll
        for (int qp = 0; qp < 2; ++qp) {
            const int qa = 2 * qp, qb = qa + 1;
            f32x4 cna, cnb, hna, hnb;
#pragma unroll
            for (int e = 0; e < 4; ++e) {
                const float ufa = __builtin_amdgcn_exp2f(acc[qa + 4][e]);
                const float ufb = __builtin_amdgcn_exp2f(acc[qb + 4][e]);
                const float dfa = 1.f + ufa, dfb = 1.f + ufb;
                const float rf = __builtin_amdgcn_rcpf(dfa * dfb);
                const float sfa = rf * dfb, sfb = rf * dfa;

                const float uia = __builtin_amdgcn_exp2f(acc[qa][e]);
                const float uib = __builtin_amdgcn_exp2f(acc[qb][e]);
                const float vga = __builtin_amdgcn_exp2f(acc[qa + 8][e]);
                const float vgb = __builtin_amdgcn_exp2f(acc[qb + 8][e]);
                const float pa = (vga - 1.f) *
                    __builtin_amdgcn_rcpf((1.f + uia) * (1.f + vga));
                const float pb = (vgb - 1.f) *
                    __builtin_amdgcn_rcpf((1.f + uib) * (1.f + vgb));

                const float ca = __builtin_fmaf(sfa, cst[qa][e], pa);
                const float cb = __builtin_fmaf(sfb, cst[qb][e], pb);
                cna[e] = ca; cnb[e] = cb;

                const float uoa = __builtin_amdgcn_exp2f(acc[qa + 12][e]);
                const float uob = __builtin_amdgcn_exp2f(acc[qb + 12][e]);
                const float vca = __builtin_amdgcn_exp2f(fminf(2.8853900817779268f * ca, 43.f));
                const float vcb = __builtin_amdgcn_exp2f(fminf(2.8853900817779268f * cb, 43.f));
                hna[e] = (vca - 1.f) * __builtin_amdgcn_rcpf((1.f + uoa) * (1.f + vca));
                hnb[e] = (vcb - 1.f) * __builtin_amdgcn_rcpf((1.f + uob) * (1.f + vcb));
            }
            cst[qa] = cna; cst[qb] = cnb;
            hvf[qa] = hna; hvf[qb] = hnb;
        }

        // next-step B fragments via packed cvt (RNE), directly as K=32 pairs
        bh01 = __builtin_bit_cast(s16x8,
                   (u32x4){pkbf(hvf[0][0], hvf[0][1]), pkbf(hvf[0][2], hvf[0][3]),
                           pkbf(hvf[1][0], hvf[1][1]), pkbf(hvf[1][2], hvf[1][3])});
        bh23 = __builtin_bit_cast(s16x8,
                   (u32x4){pkbf(hvf[2][0], hvf[2][1]), pkbf(hvf[2][2], hvf[2][3]),
                           pkbf(hvf[3][0], hvf[3][1]), pkbf(hvf[3][2], hvf[3][3])});

        // g_t raw partial, two independent chains (first shuffle at iter end)
        float gA = 0.f, gB = 0.f;
#pragma unroll
        for (int e = 0; e < 4; ++e) {
            gA = __builtin_fmaf(hvf[0][e], wg_l[0][e], gA);
            gA = __builtin_fmaf(hvf[1][e], wg_l[1][e], gA);
            gB = __builtin_fmaf(hvf[2][e], wg_l[2][e], gB);
            gB = __builtin_fmaf(hvf[3][e], wg_l[3][e], gB);
        }
        const float gpart = gA + gB;

        // out[t,cell] = gain * softplus(x-1); gain = g_t, 1, g_{t-2}
        const float x1 = xs_cur - 1.f;
        const float sp = fmaxf(x1, 0.f) +
            0.6931471805599453f * __builtin_amdgcn_logf(
                1.f + __builtin_amdgcn_exp2f(-1.4426950408889634f * fabsf(x1)));
        if (t >= 2) {
            const float gain = g2save + bg0;         // = g_{t-2}
            if (g4 == 0) {
                ON[(size_t)t * 16384 + cellidx] = gain * sp;
                if (t == 2) ON[cellidx] = gain * sp0;          // gain_0 = g_0
            }
        } else if (t == 1) {
            if (g4 == 0) ON[(size_t)16384 + cellidx] = sp;     // gain = 1
        } else {
            sp0 = sp;                                // ON[0] deferred to t==2
        }
        g2save = s2new;                              // s2 of step t-1
        g_s1 = gpart + __shfl_xor(gpart, 16, 64);    // s1 of step t
    }
}

extern "C" void kernel_launch(void* const* d_in, const int* in_sizes, int n_in,
                              void* d_out, int out_size, void* d_ws, size_t ws_size,
                              hipStream_t stream)
{
    const float* input = (const float*)d_in[0];   // [512][64][128]
    const float* W2n   = (const float*)d_in[1];   // [256][128]
    const float* b2n   = (const float*)d_in[2];   // [256]
    const float* W_ih  = (const float*)d_in[3];   // [256] (4H x 1)
    const float* W_hh  = (const float*)d_in[4];   // [256][64]
    const float* b_ih  = (const float*)d_in[5];   // [256]
    const float* b_hh  = (const float*)d_in[6];   // [256]
    const float* Wg    = (const float*)d_in[7];   // [64]  (1 x H)
    const float* bg    = (const float*)d_in[8];   // [1]
    const float* Wout  = (const float*)d_in[9];   // [64][256]
    const float* bout  = (const float*)d_in[10];  // [64]

    float* x2n = (float*)d_ws;                          // 512*16384 f32 = 32MB
    float* ON  = x2n + (size_t)512 * 16384;             // another 32MB

    // Stage 1: x2n = input @ W2n^T + b2n   (M=32768, N=256, K=128)
    gemm_xwT<<<dim3(512, 4), 256, 0, stream>>>(input, W2n, b2n, x2n, 256, 128);

    // Stage 2: recurrent scan -> ON  (1024 waves = 1/SIMD on all 256 CUs)
    lstm_scan<<<1024, 64, 0, stream>>>(x2n, W_hh, W_ih, b_ih, b_hh, Wg, bg, ON);

    // Stage 3: out = ON @ Wout^T + bout    (M=32768, N=64, K=256)
    gemm_xwT<<<dim3(512, 1), 256, 0, stream>>>(ON, Wout, bout, (float*)d_out, 64, 256);
}

// Round 12
// 834.381 us; speedup vs baseline: 1.0808x; 1.0808x over previous
//
#include <hip/hip_runtime.h>
#include <hip/hip_bf16.h>

// Problem: T=512, B=64, N=256, H=64, D=128, P=64.
// Stage 1: x2n = input(32768x128) @ W2n^T(128x256) + b2n          (gemm_xwT)
// Stage 2: 16384 independent LSTM cells scanned over 512 steps    (lstm_scan)
// Stage 3: out = ON(32768x256) @ Wout^T(256x64) + bout            (gemm_xwT)
// Workspace: x2n 32MB + ON 32MB = 64MB of d_ws.
//
// Scan (round-12) = R7 numerics (best: 866us) with the loop ROTATED to
// exploit k-slice slack in the loop-carried dependency:
//   carry acc(t) across iterations; per iteration issue
//     ext-MFMAs(t+1)   [need only x(t+1) — independent of acc(t)]
//     NL q0/q1 of acc(t) -> bh01(t)
//     ks0-MFMAs(t+1)   [need only bh01]
//     NL q2/q3 of acc(t) -> bh23(t)
//     ks1-MFMAs(t+1)   [need only bh23]
//     tail: g-reduce / softplus / ON store for step t
//   Each 16-MFMA group (~280cyc pipe) drains under the following ~976cyc
//   NL half, instead of R7's [48 MFMA serial block] -> [all NL] ordering
//   where each pipe idled while the other worked.
// Manual unroll-by-2 with accA/accB ping-pong (forceinline step fn, all
// static indices — no register copies, no scratch).  R9/R11 lesson kept:
// ext-slice stays as MFMA (free on matrix pipe); f32-init regressed twice.

typedef __attribute__((ext_vector_type(4))) float f32x4;
typedef __attribute__((ext_vector_type(4))) short s16x4;
typedef __attribute__((ext_vector_type(8))) short s16x8;
typedef __attribute__((ext_vector_type(4))) unsigned u32x4;

__device__ inline short bf16r(float f) {            // round-to-nearest-even bf16
    unsigned u = __builtin_bit_cast(unsigned, f);
    u += 0x7fffu + ((u >> 16) & 1u);
    return (short)(u >> 16);
}
__device__ inline float bf2f(short s) {
    unsigned u = ((unsigned)(unsigned short)s) << 16;
    return __builtin_bit_cast(float, u);
}
__device__ inline unsigned pkbf(float a, float b) { // (bf16(a) | bf16(b)<<16), RNE
    unsigned r;
    asm("v_cvt_pk_bf16_f32 %0, %1, %2" : "=v"(r) : "v"(a), "v"(b));
    return r;
}
__device__ inline f32x4 mfma32(s16x8 a, s16x8 b, f32x4 c) {
    return __builtin_amdgcn_mfma_f32_16x16x32_bf16(a, b, c, 0, 0, 0);
}

// ---------------------------------------------------------------------------
// Generic fp32 GEMM: Out(MxN) = X(MxK) @ Wt(NxK)^T + bias(N).  M%64==0,
// N%64==0, K%32==0.  grid = (M/64, N/64), block = 256.
// ---------------------------------------------------------------------------
__global__ __launch_bounds__(256) void gemm_xwT(
    const float* __restrict__ X, const float* __restrict__ Wt,
    const float* __restrict__ bias, float* __restrict__ Out,
    int N, int K)
{
    __shared__ float Xs[32][68];
    __shared__ float Ws[32][68];
    const int tid = threadIdx.x;
    const int tx = tid & 15, ty = tid >> 4;
    const int m0 = blockIdx.x * 64, n0 = blockIdx.y * 64;
    const int kq = tid & 7, mr = tid >> 3;

    float acc[4][4];
#pragma unroll
    for (int i = 0; i < 4; ++i)
#pragma unroll
        for (int j = 0; j < 4; ++j) acc[i][j] = 0.f;

    for (int kc = 0; kc < K; kc += 32) {
#pragma unroll
        for (int rr = 0; rr < 2; ++rr) {
            const int m = mr + rr * 32;
            f32x4 xv = *(const f32x4*)(X + (size_t)(m0 + m) * K + kc + kq * 4);
            f32x4 wv = *(const f32x4*)(Wt + (size_t)(n0 + m) * K + kc + kq * 4);
#pragma unroll
            for (int j = 0; j < 4; ++j) { Xs[kq*4 + j][m] = xv[j]; Ws[kq*4 + j][m] = wv[j]; }
        }
        __syncthreads();
#pragma unroll
        for (int k = 0; k < 32; ++k) {
            f32x4 a = *(const f32x4*)&Xs[k][ty * 4];
            f32x4 b = *(const f32x4*)&Ws[k][tx * 4];
#pragma unroll
            for (int i = 0; i < 4; ++i)
#pragma unroll
                for (int j = 0; j < 4; ++j)
                    acc[i][j] = __builtin_fmaf(a[i], b[j], acc[i][j]);
        }
        __syncthreads();
    }
    f32x4 bv = *(const f32x4*)(bias + n0 + tx * 4);
#pragma unroll
    for (int i = 0; i < 4; ++i) {
        f32x4 o;
#pragma unroll
        for (int j = 0; j < 4; ++j) o[j] = acc[i][j] + bv[j];
        *(f32x4*)(Out + (size_t)(m0 + ty * 4 + i) * N + n0 + tx * 4) = o;
    }
}

// ---------------------------------------------------------------------------
// One rotated scan step: consumes acc (gates of step t, pre-scaled),
// produces accn (gates of step t+1) and the step-t output.
// MFMA 16x16x32 bf16 layouts, lane l, c15=l&15, g4=l>>4:
//   A: lane elems 0-3 hold A[c15][4*g4+e], elems 4-7: +16
//   B: lane elems 0-3 hold B[4*g4+e][c15], elems 4-7: +16
//   D: lane reg e holds D[4*g4+e][c15]
// Tile nt = type*4 + q (type 0..3 = i,f,g,o); scale -log2e (i,f,o) /
// +2log2e (g) baked into A fragments.
// ---------------------------------------------------------------------------
__device__ __attribute__((always_inline)) inline void lstm_step(
    const int t,
    f32x4 (&acc)[16], f32x4 (&accn)[16],
    const s16x8 (&afw8)[2][16], const s16x8 (&afx8)[16],
    f32x4 (&cst)[4], const f32x4 (&wg_l)[4],
    float& g_s1, float& g2save, float& sp0,
    float& xs0, float& xs1,
    const float bg0, const int g4, const size_t cellidx,
    const float* __restrict__ x2n, float* __restrict__ ON)
{
    // finish step t-1's g-reduction (independent)
    const float s2new = g_s1 + __shfl_xor(g_s1, 32, 64);

    const float xs_cur = xs0;
    const float xs_new = x2n[(size_t)((t + 2) & 511) * 16384 + cellidx];

    // ---- ext-slice MFMAs for step t+1 (need only x(t+1) = xs1) ----
    const short one_bf = (short)0x3F80;
    const short xh = bf16r(xs1);
    const short xl = bf16r(xs1 - bf2f(xh));
    s16x8 bx8 = (s16x8){0, 0, 0, 0, 0, 0, 0, 0};
    if (g4 == 0) { bx8[0] = xh; bx8[1] = xl; bx8[2] = xh; bx8[3] = one_bf; }
    else if (g4 == 1) { bx8[0] = one_bf; }
    const f32x4 zero4 = (f32x4){0.f, 0.f, 0.f, 0.f};
#pragma unroll
    for (int nt = 0; nt < 16; ++nt) accn[nt] = mfma32(afx8[nt], bx8, zero4);

    // ---- NL for q=0,1 of step t (matrix pipe drains ext under this) ----
    f32x4 hvf0, hvf1;
    {
        f32x4 cna, cnb, hna, hnb;
#pragma unroll
        for (int e = 0; e < 4; ++e) {
            const float ufa = __builtin_amdgcn_exp2f(acc[4][e]);
            const float ufb = __builtin_amdgcn_exp2f(acc[5][e]);
            const float dfa = 1.f + ufa, dfb = 1.f + ufb;
            const float rf = __builtin_amdgcn_rcpf(dfa * dfb);
            const float sfa = rf * dfb, sfb = rf * dfa;

            const float uia = __builtin_amdgcn_exp2f(acc[0][e]);
            const float uib = __builtin_amdgcn_exp2f(acc[1][e]);
            const float vga = __builtin_amdgcn_exp2f(acc[8][e]);
            const float vgb = __builtin_amdgcn_exp2f(acc[9][e]);
            const float pa = (vga - 1.f) *
                __builtin_amdgcn_rcpf((1.f + uia) * (1.f + vga));
            const float pb = (vgb - 1.f) *
                __builtin_amdgcn_rcpf((1.f + uib) * (1.f + vgb));

            const float ca = __builtin_fmaf(sfa, cst[0][e], pa);
            const float cb = __builtin_fmaf(sfb, cst[1][e], pb);
            cna[e] = ca; cnb[e] = cb;

            const float uoa = __builtin_amdgcn_exp2f(acc[12][e]);
            const float uob = __builtin_amdgcn_exp2f(acc[13][e]);
            const float vca = __builtin_amdgcn_exp2f(fminf(2.8853900817779268f * ca, 43.f));
            const float vcb = __builtin_amdgcn_exp2f(fminf(2.8853900817779268f * cb, 43.f));
            hna[e] = (vca - 1.f) * __builtin_amdgcn_rcpf((1.f + uoa) * (1.f + vca));
            hnb[e] = (vcb - 1.f) * __builtin_amdgcn_rcpf((1.f + uob) * (1.f + vcb));
        }
        cst[0] = cna; cst[1] = cnb;
        hvf0 = hna; hvf1 = hnb;
    }
    const s16x8 bh01 = __builtin_bit_cast(s16x8,
        (u32x4){pkbf(hvf0[0], hvf0[1]), pkbf(hvf0[2], hvf0[3]),
                pkbf(hvf1[0], hvf1[1]), pkbf(hvf1[2], hvf1[3])});
#pragma unroll
    for (int nt = 0; nt < 16; ++nt) accn[nt] = mfma32(afw8[0][nt], bh01, accn[nt]);

    // ---- NL for q=2,3 of step t (ks0 MFMAs drain under this) ----
    f32x4 hvf2, hvf3;
    {
        f32x4 cna, cnb, hna, hnb;
#pragma unroll
        for (int e = 0; e < 4; ++e) {
            const float ufa = __builtin_amdgcn_exp2f(acc[6][e]);
            const float ufb = __builtin_amdgcn_exp2f(acc[7][e]);
            const float dfa = 1.f + ufa, dfb = 1.f + ufb;
            const float rf = __builtin_amdgcn_rcpf(dfa * dfb);
            const float sfa = rf * dfb, sfb = rf * dfa;

            const float uia = __builtin_amdgcn_exp2f(acc[2][e]);
            const float uib = __builtin_amdgcn_exp2f(acc[3][e]);
            const float vga = __builtin_amdgcn_exp2f(acc[10][e]);
            const float vgb = __builtin_amdgcn_exp2f(acc[11][e]);
            const float pa = (vga - 1.f) *
                __builtin_amdgcn_rcpf((1.f + uia) * (1.f + vga));
            const float pb = (vgb - 1.f) *
                __builtin_amdgcn_rcpf((1.f + uib) * (1.f + vgb));

            const float ca = __builtin_fmaf(sfa, cst[2][e], pa);
            const float cb = __builtin_fmaf(sfb, cst[3][e], pb);
            cna[e] = ca; cnb[e] = cb;

            const float uoa = __builtin_amdgcn_exp2f(acc[14][e]);
            const float uob = __builtin_amdgcn_exp2f(acc[15][e]);
            const float vca = __builtin_amdgcn_exp2f(fminf(2.8853900817779268f * ca, 43.f));
            const float vcb = __builtin_amdgcn_exp2f(fminf(2.8853900817779268f * cb, 43.f));
            hna[e] = (vca - 1.f) * __builtin_amdgcn_rcpf((1.f + uoa) * (1.f + vca));
            hnb[e] = (vcb - 1.f) * __builtin_amdgcn_rcpf((1.f + uob) * (1.f + vcb));
        }
        cst[2] = cna; cst[3] = cnb;
        hvf2 = hna; hvf3 = hnb;
    }
    const s16x8 bh23 = __builtin_bit_cast(s16x8,
        (u32x4){pkbf(hvf2[0], hvf2[1]), pkbf(hvf2[2], hvf2[3]),
                pkbf(hvf3[0], hvf3[1]), pkbf(hvf3[2], hvf3[3])});
#pragma unroll
    for (int nt = 0; nt < 16; ++nt) accn[nt] = mfma32(afw8[1][nt], bh23, accn[nt]);

    // ---- tail for step t (ks1 MFMAs drain under this) ----
    float gA = 0.f, gB = 0.f;
#pragma unroll
    for (int e = 0; e < 4; ++e) {
        gA = __builtin_fmaf(hvf0[e], wg_l[0][e], gA);
        gA = __builtin_fmaf(hvf1[e], wg_l[1][e], gA);
        gB = __builtin_fmaf(hvf2[e], wg_l[2][e], gB);
        gB = __builtin_fmaf(hvf3[e], wg_l[3][e], gB);
    }
    const float gpart = gA + gB;

    const float x1 = xs_cur - 1.f;
    const float sp = fmaxf(x1, 0.f) +
        0.6931471805599453f * __builtin_amdgcn_logf(
            1.f + __builtin_amdgcn_exp2f(-1.4426950408889634f * fabsf(x1)));
    if (t >= 2) {
        const float gain = g2save + bg0;             // = g_{t-2}
        if (g4 == 0) {
            ON[(size_t)t * 16384 + cellidx] = gain * sp;
            if (t == 2) ON[cellidx] = gain * sp0;    // gain_0 = g_0
        }
    } else if (t == 1) {
        if (g4 == 0) ON[(size_t)16384 + cellidx] = sp;   // gain = 1
    } else {
        sp0 = sp;                                    // ON[0] deferred to t==2
    }
    g2save = s2new;                                  // s2 of step t-1
    g_s1 = gpart + __shfl_xor(gpart, 16, 64);        // s1 of step t
    xs0 = xs1;
    xs1 = xs_new;
}

// ---------------------------------------------------------------------------
// Recurrent scan.  1024 blocks x 64 threads; each wave owns 16 cells for all
// 512 steps; 1 wave/SIMD; full 512-VGPR budget (waves_per_eu(1,1)).
// ---------------------------------------------------------------------------
__global__
__attribute__((amdgpu_flat_work_group_size(64, 64)))
__attribute__((amdgpu_waves_per_eu(1, 1)))
void lstm_scan(
    const float* __restrict__ x2n,   // [512][16384]
    const float* __restrict__ W_hh,  // [256][64]
    const float* __restrict__ w_ih,  // [256]
    const float* __restrict__ b_ih,  // [256]
    const float* __restrict__ b_hh,  // [256]
    const float* __restrict__ wg,    // [64]
    const float* __restrict__ bg,    // [1]
    float* __restrict__ ON)          // [512][16384]
{
    const int lane = threadIdx.x & 63;
    const int c15 = lane & 15, g4 = lane >> 4;
    const int cellbase = blockIdx.x * 16;
    const float L2E = 1.4426950408889634f;

    // W_hh A-fragments (K=32 pairs) + ext-slice fragments, PRE-SCALED.
    s16x8 afw8[2][16];
    s16x8 afx8[16];
#pragma unroll
    for (int nt = 0; nt < 16; ++nt) {
        const float sc = ((nt >> 2) == 2) ? (2.f * L2E) : (-L2E);
        const float* wrow = W_hh + (size_t)(nt * 16 + c15) * 64;
#pragma unroll
        for (int kp = 0; kp < 2; ++kp) {
            s16x8 v;
#pragma unroll
            for (int half = 0; half < 2; ++half) {
                f32x4 w = *(const f32x4*)(wrow + (kp * 2 + half) * 16 + g4 * 4);
#pragma unroll
                for (int e = 0; e < 4; ++e) v[half * 4 + e] = bf16r(w[e] * sc);
            }
            afw8[kp][nt] = v;
        }
        // Ext slice A row, paired with B-ext (xh, xl, xh, 1 | 1); hi half 0.
        const int g = nt * 16 + c15;
        const float wi = w_ih[g] * sc;
        const float bs = (b_ih[g] + b_hh[g]) * sc;
        const short wh = bf16r(wi);
        const short wl = bf16r(wi - bf2f(wh));
        const short bh_ = bf16r(bs);
        const short bl_ = bf16r(bs - bf2f(bh_));
        s16x8 v = (s16x8){0, 0, 0, 0, 0, 0, 0, 0};
        if (g4 == 0) { v[0] = wh; v[1] = wh; v[2] = wl; v[3] = bh_; }
        else if (g4 == 1) { v[0] = bl_; }
        afx8[nt] = v;
    }

    // wg, laid out to match hvf: wg_l[q][e] = wg[q*16 + 4*g4 + e]
    f32x4 wg_l[4];
#pragma unroll
    for (int q = 0; q < 4; ++q) wg_l[q] = *(const f32x4*)(wg + q * 16 + g4 * 4);
    const float bg0 = bg[0];

    f32x4 cst[4];
#pragma unroll
    for (int q = 0; q < 4; ++q) cst[q] = (f32x4){0.f, 0.f, 0.f, 0.f};

    float g_s1 = 0.f, g2save = 0.f, sp0 = 0.f;

    const size_t cellidx = (size_t)cellbase + c15;
    float xs0 = x2n[cellidx];                        // x(t)
    float xs1 = x2n[(size_t)16384 + cellidx];        // x(t+1)

    // Prologue: acc(0) = ext(x(0))   (h(-1) = 0 -> no W_hh terms)
    f32x4 accA[16], accB[16];
    {
        const short one_bf = (short)0x3F80;
        const short xh = bf16r(xs0);
        const short xl = bf16r(xs0 - bf2f(xh));
        s16x8 bx8 = (s16x8){0, 0, 0, 0, 0, 0, 0, 0};
        if (g4 == 0) { bx8[0] = xh; bx8[1] = xl; bx8[2] = xh; bx8[3] = one_bf; }
        else if (g4 == 1) { bx8[0] = one_bf; }
        const f32x4 zero4 = (f32x4){0.f, 0.f, 0.f, 0.f};
#pragma unroll
        for (int nt = 0; nt < 16; ++nt) accA[nt] = mfma32(afx8[nt], bx8, zero4);
    }

    for (int t = 0; t < 512; t += 2) {
        lstm_step(t,     accA, accB, afw8, afx8, cst, wg_l,
                  g_s1, g2save, sp0, xs0, xs1, bg0, g4, cellidx, x2n, ON);
        lstm_step(t + 1, accB, accA, afw8, afx8, cst, wg_l,
                  g_s1, g2save, sp0, xs0, xs1, bg0, g4, cellidx, x2n, ON);
    }
}

extern "C" void kernel_launch(void* const* d_in, const int* in_sizes, int n_in,
                              void* d_out, int out_size, void* d_ws, size_t ws_size,
                              hipStream_t stream)
{
    const float* input = (const float*)d_in[0];   // [512][64][128]
    const float* W2n   = (const float*)d_in[1];   // [256][128]
    const float* b2n   = (const float*)d_in[2];   // [256]
    const float* W_ih  = (const float*)d_in[3];   // [256] (4H x 1)
    const float* W_hh  = (const float*)d_in[4];   // [256][64]
    const float* b_ih  = (const float*)d_in[5];   // [256]
    const float* b_hh  = (const float*)d_in[6];   // [256]
    const float* Wg    = (const float*)d_in[7];   // [64]  (1 x H)
    const float* bg    = (const float*)d_in[8];   // [1]
    const float* Wout  = (const float*)d_in[9];   // [64][256]
    const float* bout  = (const float*)d_in[10];  // [64]

    float* x2n = (float*)d_ws;                          // 512*16384 f32 = 32MB
    float* ON  = x2n + (size_t)512 * 16384;             // another 32MB

    // Stage 1: x2n = input @ W2n^T + b2n   (M=32768, N=256, K=128)
    gemm_xwT<<<dim3(512, 4), 256, 0, stream>>>(input, W2n, b2n, x2n, 256, 128);

    // Stage 2: recurrent scan -> ON  (1024 waves = 1/SIMD on all 256 CUs)
    lstm_scan<<<1024, 64, 0, stream>>>(x2n, W_hh, W_ih, b_ih, b_hh, Wg, bg, ON);

    // Stage 3: out = ON @ Wout^T + bout    (M=32768, N=64, K=256)
    gemm_xwT<<<dim3(512, 1), 256, 0, stream>>>(ON, Wout, bout, (float*)d_out, 64, 256);
}

// Round 13
// 822.378 us; speedup vs baseline: 1.0966x; 1.0146x over previous
//
#include <hip/hip_runtime.h>
#include <hip/hip_bf16.h>

// Problem: T=512, B=64, N=256, H=64, D=128, P=64.
// Stage 1: x2n = input(32768x128) @ W2n^T(128x256) + b2n          (gemm_xwT)
// Stage 2: 16384 independent LSTM cells scanned over 512 steps    (lstm_scan)
// Stage 3: out = ON(32768x256) @ Wout^T(256x64) + bout            (gemm_xwT)
// Workspace: x2n 32MB + ON 32MB = 64MB of d_ws.
//
// Scan (round-13) = R7 champion (866us scan) + ONE change: pair the p-term
// and h-term rcps across the (qa,qb) element pair, like rf already is:
//   rp = rcp(Da*Db); pa = (vga-1)*(Db*rp); pb = (vgb-1)*(Da*rp)
// -2 rcp (+6 mul) per pair-iteration = -160 cyc/step on the additive model
// (R9/R10/R12 established: at 1 wave/SIMD MFMA blocks its wave, so step =
// trans + VALU + MFMA + waits, strictly additive; only term-cuts help).
// NaN-safety: products parenthesized (v-1)*(D*r) so overflowed pair-products
// give finite*0=0 (correct saturation limit), never inf*0=NaN; single
// denominators cannot overflow (max exponent sum ~75 < 88; vc clamped at 43).

typedef __attribute__((ext_vector_type(4))) float f32x4;
typedef __attribute__((ext_vector_type(4))) short s16x4;
typedef __attribute__((ext_vector_type(8))) short s16x8;
typedef __attribute__((ext_vector_type(4))) unsigned u32x4;

__device__ inline short bf16r(float f) {            // round-to-nearest-even bf16
    unsigned u = __builtin_bit_cast(unsigned, f);
    u += 0x7fffu + ((u >> 16) & 1u);
    return (short)(u >> 16);
}
__device__ inline float bf2f(short s) {
    unsigned u = ((unsigned)(unsigned short)s) << 16;
    return __builtin_bit_cast(float, u);
}
__device__ inline unsigned pkbf(float a, float b) { // (bf16(a) | bf16(b)<<16), RNE
    unsigned r;
    asm("v_cvt_pk_bf16_f32 %0, %1, %2" : "=v"(r) : "v"(a), "v"(b));
    return r;
}
__device__ inline f32x4 mfma32(s16x8 a, s16x8 b, f32x4 c) {
    return __builtin_amdgcn_mfma_f32_16x16x32_bf16(a, b, c, 0, 0, 0);
}

// ---------------------------------------------------------------------------
// Generic fp32 GEMM: Out(MxN) = X(MxK) @ Wt(NxK)^T + bias(N).  M%64==0,
// N%64==0, K%32==0.  grid = (M/64, N/64), block = 256.
// ---------------------------------------------------------------------------
__global__ __launch_bounds__(256) void gemm_xwT(
    const float* __restrict__ X, const float* __restrict__ Wt,
    const float* __restrict__ bias, float* __restrict__ Out,
    int N, int K)
{
    __shared__ float Xs[32][68];
    __shared__ float Ws[32][68];
    const int tid = threadIdx.x;
    const int tx = tid & 15, ty = tid >> 4;
    const int m0 = blockIdx.x * 64, n0 = blockIdx.y * 64;
    const int kq = tid & 7, mr = tid >> 3;

    float acc[4][4];
#pragma unroll
    for (int i = 0; i < 4; ++i)
#pragma unroll
        for (int j = 0; j < 4; ++j) acc[i][j] = 0.f;

    for (int kc = 0; kc < K; kc += 32) {
#pragma unroll
        for (int rr = 0; rr < 2; ++rr) {
            const int m = mr + rr * 32;
            f32x4 xv = *(const f32x4*)(X + (size_t)(m0 + m) * K + kc + kq * 4);
            f32x4 wv = *(const f32x4*)(Wt + (size_t)(n0 + m) * K + kc + kq * 4);
#pragma unroll
            for (int j = 0; j < 4; ++j) { Xs[kq*4 + j][m] = xv[j]; Ws[kq*4 + j][m] = wv[j]; }
        }
        __syncthreads();
#pragma unroll
        for (int k = 0; k < 32; ++k) {
            f32x4 a = *(const f32x4*)&Xs[k][ty * 4];
            f32x4 b = *(const f32x4*)&Ws[k][tx * 4];
#pragma unroll
            for (int i = 0; i < 4; ++i)
#pragma unroll
                for (int j = 0; j < 4; ++j)
                    acc[i][j] = __builtin_fmaf(a[i], b[j], acc[i][j]);
        }
        __syncthreads();
    }
    f32x4 bv = *(const f32x4*)(bias + n0 + tx * 4);
#pragma unroll
    for (int i = 0; i < 4; ++i) {
        f32x4 o;
#pragma unroll
        for (int j = 0; j < 4; ++j) o[j] = acc[i][j] + bv[j];
        *(f32x4*)(Out + (size_t)(m0 + ty * 4 + i) * N + n0 + tx * 4) = o;
    }
}

// ---------------------------------------------------------------------------
// Recurrent scan, register-only h.  1024 blocks x 64 threads; each wave owns
// 16 cells (cell = cellbase + (lane&15)) for all 512 steps.
//
// MFMA 16x16x32 bf16 layouts, lane l, c15=l&15, g4=l>>4:
//   A: lane elems 0-3 hold A[c15][kbase + 4*g4 + e], elems 4-7: +16
//   B: lane elems 0-3 hold B[kbase + 4*g4 + e][c15], elems 4-7: +16
//   D: lane reg e holds D[4*g4 + e][c15]
//
// acc[nt] (nt=0..15): lane (g4,c15) elem e = PRE-SCALED gate nt*16+4g4+e of
// cell c15; type=nt>>2 in {i,f,g,o}; scale -log2e for i/f/o, +2log2e for g.
// ---------------------------------------------------------------------------
__global__ __launch_bounds__(64, 1) void lstm_scan(
    const float* __restrict__ x2n,   // [512][16384]
    const float* __restrict__ W_hh,  // [256][64]
    const float* __restrict__ w_ih,  // [256]
    const float* __restrict__ b_ih,  // [256]
    const float* __restrict__ b_hh,  // [256]
    const float* __restrict__ wg,    // [64]
    const float* __restrict__ bg,    // [1]
    float* __restrict__ ON)          // [512][16384]
{
    const int lane = threadIdx.x & 63;
    const int c15 = lane & 15, g4 = lane >> 4;
    const int cellbase = blockIdx.x * 16;

    const float L2E = 1.4426950408889634f;   // log2(e)

    // W_hh A-fragments (K=32 pairs) + ext-slice fragments, PRE-SCALED.
    s16x8 afw8[2][16];
    s16x8 afx8[16];
#pragma unroll
    for (int nt = 0; nt < 16; ++nt) {
        const float sc = ((nt >> 2) == 2) ? (2.f * L2E) : (-L2E);
        const float* wrow = W_hh + (size_t)(nt * 16 + c15) * 64;
#pragma unroll
        for (int kp = 0; kp < 2; ++kp) {
            s16x8 v;
#pragma unroll
            for (int half = 0; half < 2; ++half) {
                f32x4 w = *(const f32x4*)(wrow + (kp * 2 + half) * 16 + g4 * 4);
#pragma unroll
                for (int e = 0; e < 4; ++e) v[half * 4 + e] = bf16r(w[e] * sc);
            }
            afw8[kp][nt] = v;
        }
        // Ext slice A row, paired with B-ext (xh, xl, xh, 1 | 1); hi half 0.
        const int g = nt * 16 + c15;
        const float wi = w_ih[g] * sc;
        const float bs = (b_ih[g] + b_hh[g]) * sc;
        const short wh = bf16r(wi);
        const short wl = bf16r(wi - bf2f(wh));
        const short bh_ = bf16r(bs);
        const short bl_ = bf16r(bs - bf2f(bh_));
        s16x8 v = (s16x8){0, 0, 0, 0, 0, 0, 0, 0};
        if (g4 == 0) { v[0] = wh; v[1] = wh; v[2] = wl; v[3] = bh_; }
        else if (g4 == 1) { v[0] = bl_; }
        afx8[nt] = v;
    }
    // Pin weight fragments (one-time; same as R7 champion).
#pragma unroll
    for (int nt = 0; nt < 16; ++nt) {
        asm volatile("" : "+v"(afw8[0][nt]));
        asm volatile("" : "+v"(afw8[1][nt]));
        asm volatile("" : "+v"(afx8[nt]));
    }

    // wg, laid out to match hvf: wg_l[q][e] = wg[q*16 + 4*g4 + e]
    f32x4 wg_l[4];
#pragma unroll
    for (int q = 0; q < 4; ++q) wg_l[q] = *(const f32x4*)(wg + q * 16 + g4 * 4);
    const float bg0 = bg[0];
    const short one_bf = (short)0x3F80;

    f32x4 cst[4];
#pragma unroll
    for (int q = 0; q < 4; ++q) cst[q] = (f32x4){0.f, 0.f, 0.f, 0.f};
    s16x8 bh01 = (s16x8){0, 0, 0, 0, 0, 0, 0, 0};   // h k=0..31  B-fragment
    s16x8 bh23 = (s16x8){0, 0, 0, 0, 0, 0, 0, 0};   // h k=32..63 B-fragment

    float g_s1 = 0.f;      // xor16-reduced g-partial of step t-1
    float g2save = 0.f;    // fully-reduced g of step t-2
    float sp0 = 0.f;

    const size_t cellidx = (size_t)cellbase + c15;
    float xs = x2n[cellidx];          // x for (t=0, cell c15), prefetched

    for (int t = 0; t < 512; ++t) {
        // finish step t-1's g-reduction (independent of everything below)
        const float s2new = g_s1 + __shfl_xor(g_s1, 32, 64);

        // B extension fragment from x (hi/lo bf16 split), hi half zero
        const float xs_cur = xs;
        const short xh = bf16r(xs_cur);
        const short xl = bf16r(xs_cur - bf2f(xh));
        s16x8 bx8 = (s16x8){0, 0, 0, 0, 0, 0, 0, 0};
        if (g4 == 0) { bx8[0] = xh; bx8[1] = xl; bx8[2] = xh; bx8[3] = one_bf; }
        else if (g4 == 1) { bx8[0] = one_bf; }
        xs = x2n[(size_t)((t + 1) & 511) * 16384 + cellidx]; // branchless prefetch

        // gates^T (pre-scaled): ext K-slice + two K=32 slices of W_hh @ h^T
        f32x4 acc[16];
        const f32x4 zero4 = (f32x4){0.f, 0.f, 0.f, 0.f};
#pragma unroll
        for (int nt = 0; nt < 16; ++nt) acc[nt] = mfma32(afx8[nt], bx8, zero4);
#pragma unroll
        for (int nt = 0; nt < 16; ++nt) acc[nt] = mfma32(afw8[0][nt], bh01, acc[nt]);
#pragma unroll
        for (int nt = 0; nt < 16; ++nt) acc[nt] = mfma32(afw8[1][nt], bh23, acc[nt]);

        // ---- merged nonlinearities, ALL rcps paired across (qa,qb) ----
        f32x4 hvf[4];
#pragma unroll
        for (int qp = 0; qp < 2; ++qp) {
            const int qa = 2 * qp, qb = qa + 1;
            f32x4 cna, cnb, hna, hnb;
#pragma unroll
            for (int e = 0; e < 4; ++e) {
                // sig(f) pair: rf = rcp(dfa*dfb)
                const float ufa = __builtin_amdgcn_exp2f(acc[qa + 4][e]);
                const float ufb = __builtin_amdgcn_exp2f(acc[qb + 4][e]);
                const float dfa = 1.f + ufa, dfb = 1.f + ufb;
                const float rf = __builtin_amdgcn_rcpf(dfa * dfb);
                const float sfa = rf * dfb, sfb = rf * dfa;

                // sig(i)*tanh(g) pair: rp = rcp(Da*Db)
                const float uia = __builtin_amdgcn_exp2f(acc[qa][e]);
                const float uib = __builtin_amdgcn_exp2f(acc[qb][e]);
                const float vga = __builtin_amdgcn_exp2f(acc[qa + 8][e]);
                const float vgb = __builtin_amdgcn_exp2f(acc[qb + 8][e]);
                const float Da = (1.f + uia) * (1.f + vga);
                const float Db = (1.f + uib) * (1.f + vgb);
                const float rp = __builtin_amdgcn_rcpf(Da * Db);
                // order (v-1)*(D*rp): if Da*Db overflowed, rp=0 and D*rp=0
                // (D finite), giving the correct saturation limit, no NaN.
                const float pa = (vga - 1.f) * (Db * rp);
                const float pb = (vgb - 1.f) * (Da * rp);

                const float ca = __builtin_fmaf(sfa, cst[qa][e], pa);
                const float cb = __builtin_fmaf(sfb, cst[qb][e], pb);
                cna[e] = ca; cnb[e] = cb;

                // sig(o)*tanh(c') pair: rh = rcp(Ea*Eb); vc clamp keeps E finite
                const float uoa = __builtin_amdgcn_exp2f(acc[qa + 12][e]);
                const float uob = __builtin_amdgcn_exp2f(acc[qb + 12][e]);
                const float vca = __builtin_amdgcn_exp2f(fminf(2.8853900817779268f * ca, 43.f));
                const float vcb = __builtin_amdgcn_exp2f(fminf(2.8853900817779268f * cb, 43.f));
                const float Ea = (1.f + uoa) * (1.f + vca);
                const float Eb = (1.f + uob) * (1.f + vcb);
                const float rh = __builtin_amdgcn_rcpf(Ea * Eb);
                hna[e] = (vca - 1.f) * (Eb * rh);
                hnb[e] = (vcb - 1.f) * (Ea * rh);
            }
            cst[qa] = cna; cst[qb] = cnb;
            hvf[qa] = hna; hvf[qb] = hnb;
        }

        // next-step B fragments via packed cvt (RNE), directly as K=32 pairs
        bh01 = __builtin_bit_cast(s16x8,
                   (u32x4){pkbf(hvf[0][0], hvf[0][1]), pkbf(hvf[0][2], hvf[0][3]),
                           pkbf(hvf[1][0], hvf[1][1]), pkbf(hvf[1][2], hvf[1][3])});
        bh23 = __builtin_bit_cast(s16x8,
                   (u32x4){pkbf(hvf[2][0], hvf[2][1]), pkbf(hvf[2][2], hvf[2][3]),
                           pkbf(hvf[3][0], hvf[3][1]), pkbf(hvf[3][2], hvf[3][3])});

        // g_t raw partial; first reduction stage at iter end (stage 2 next iter)
        float gpart = 0.f;
#pragma unroll
        for (int q = 0; q < 4; ++q)
#pragma unroll
            for (int e = 0; e < 4; ++e)
                gpart = __builtin_fmaf(hvf[q][e], wg_l[q][e], gpart);

        // out[t,cell] = gain * softplus(x-1); gain = g_t, 1, g_{t-2}
        const float x1 = xs_cur - 1.f;
        const float sp = fmaxf(x1, 0.f) +
            0.6931471805599453f * __builtin_amdgcn_logf(
                1.f + __builtin_amdgcn_exp2f(-1.4426950408889634f * fabsf(x1)));
        if (t >= 2) {
            const float gain = g2save + bg0;         // = g_{t-2}
            if (g4 == 0) {
                ON[(size_t)t * 16384 + cellidx] = gain * sp;
                if (t == 2) ON[cellidx] = gain * sp0;          // gain_0 = g_0
            }
        } else if (t == 1) {
            if (g4 == 0) ON[(size_t)16384 + cellidx] = sp;     // gain = 1
        } else {
            sp0 = sp;                                // ON[0] deferred to t==2
        }
        g2save = s2new;                              // s2 of step t-1
        g_s1 = gpart + __shfl_xor(gpart, 16, 64);    // s1 of step t
    }
}

extern "C" void kernel_launch(void* const* d_in, const int* in_sizes, int n_in,
                              void* d_out, int out_size, void* d_ws, size_t ws_size,
                              hipStream_t stream)
{
    const float* input = (const float*)d_in[0];   // [512][64][128]
    const float* W2n   = (const float*)d_in[1];   // [256][128]
    const float* b2n   = (const float*)d_in[2];   // [256]
    const float* W_ih  = (const float*)d_in[3];   // [256] (4H x 1)
    const float* W_hh  = (const float*)d_in[4];   // [256][64]
    const float* b_ih  = (const float*)d_in[5];   // [256]
    const float* b_hh  = (const float*)d_in[6];   // [256]
    const float* Wg    = (const float*)d_in[7];   // [64]  (1 x H)
    const float* bg    = (const float*)d_in[8];   // [1]
    const float* Wout  = (const float*)d_in[9];   // [64][256]
    const float* bout  = (const float*)d_in[10];  // [64]

    float* x2n = (float*)d_ws;                          // 512*16384 f32 = 32MB
    float* ON  = x2n + (size_t)512 * 16384;             // another 32MB

    // Stage 1: x2n = input @ W2n^T + b2n   (M=32768, N=256, K=128)
    gemm_xwT<<<dim3(512, 4), 256, 0, stream>>>(input, W2n, b2n, x2n, 256, 128);

    // Stage 2: recurrent scan -> ON  (1024 waves = 1/SIMD on all 256 CUs)
    lstm_scan<<<1024, 64, 0, stream>>>(x2n, W_hh, W_ih, b_ih, b_hh, Wg, bg, ON);

    // Stage 3: out = ON @ Wout^T + bout    (M=32768, N=64, K=256)
    gemm_xwT<<<dim3(512, 1), 256, 0, stream>>>(ON, Wout, bout, (float*)d_out, 64, 256);
}

// Round 14
// 788.006 us; speedup vs baseline: 1.1444x; 1.0436x over previous
//
#include <hip/hip_runtime.h>
#include <hip/hip_bf16.h>

// Problem: T=512, B=64, N=256, H=64, D=128, P=64.
// Stage 1: x2n = input(32768x128) @ W2n^T(128x256) + b2n          (gemm_xwT)
// Stage 2: 16384 independent LSTM cells scanned over 512 steps    (lstm_scan)
// Stage 3: out = ON(32768x256) @ Wout^T(256x64) + bout            (gemm_xwT)
// Workspace: x2n 32MB + ON 32MB = 64MB of d_ws.
//
// Scan (round-14) = R13 + two MFMA-pipe cuts (additive model, R12-verified):
//   - ext-slice MFMAs use 16x16x16 (K=16 covers the 8 ext k-slots) — half
//     the pipe occupancy of the K=32 shape for the same result (~-130cyc).
//   - g_t = wg.h computed by 2 MFMAs (A row0 = wg, rows 1-15 = 0; D[0][c15]
//     lands in reg0 of lanes g4==0 — exactly the ON-storing lanes).
//     Replaces 16 FMA + 2 ds_swizzle shuffles + 2-stage deferred reduce.
//     Result read 2 steps later (gain_t = g_{t-2} slack) -> latency hidden.
//   R13 lesson kept: acc init stays on the MFMA pipe (f32 VALU init forces
//   per-step cross-file accumulator moves — regressed twice, R9/R11).

typedef __attribute__((ext_vector_type(4))) float f32x4;
typedef __attribute__((ext_vector_type(4))) short s16x4;
typedef __attribute__((ext_vector_type(8))) short s16x8;
typedef __attribute__((ext_vector_type(4))) unsigned u32x4;

__device__ inline short bf16r(float f) {            // round-to-nearest-even bf16
    unsigned u = __builtin_bit_cast(unsigned, f);
    u += 0x7fffu + ((u >> 16) & 1u);
    return (short)(u >> 16);
}
__device__ inline float bf2f(short s) {
    unsigned u = ((unsigned)(unsigned short)s) << 16;
    return __builtin_bit_cast(float, u);
}
__device__ inline unsigned pkbf(float a, float b) { // (bf16(a) | bf16(b)<<16), RNE
    unsigned r;
    asm("v_cvt_pk_bf16_f32 %0, %1, %2" : "=v"(r) : "v"(a), "v"(b));
    return r;
}
__device__ inline f32x4 mfma32(s16x8 a, s16x8 b, f32x4 c) {
    return __builtin_amdgcn_mfma_f32_16x16x32_bf16(a, b, c, 0, 0, 0);
}
__device__ inline s16x8 cat8(s16x4 a, s16x4 b) {
    s16x8 r;
    r[0]=a[0]; r[1]=a[1]; r[2]=a[2]; r[3]=a[3];
    r[4]=b[0]; r[5]=b[1]; r[6]=b[2]; r[7]=b[3];
    return r;
}
#if __has_builtin(__builtin_amdgcn_mfma_f32_16x16x16bf16_1k)
#define HAVE_MFMA16 1
__device__ inline f32x4 mfma16(s16x4 a, s16x4 b, f32x4 c) {
    return __builtin_amdgcn_mfma_f32_16x16x16bf16_1k(a, b, c, 0, 0, 0);
}
#else
#define HAVE_MFMA16 0
#endif

// ---------------------------------------------------------------------------
// Generic fp32 GEMM: Out(MxN) = X(MxK) @ Wt(NxK)^T + bias(N).  M%64==0,
// N%64==0, K%32==0.  grid = (M/64, N/64), block = 256.
// ---------------------------------------------------------------------------
__global__ __launch_bounds__(256) void gemm_xwT(
    const float* __restrict__ X, const float* __restrict__ Wt,
    const float* __restrict__ bias, float* __restrict__ Out,
    int N, int K)
{
    __shared__ float Xs[32][68];
    __shared__ float Ws[32][68];
    const int tid = threadIdx.x;
    const int tx = tid & 15, ty = tid >> 4;
    const int m0 = blockIdx.x * 64, n0 = blockIdx.y * 64;
    const int kq = tid & 7, mr = tid >> 3;

    float acc[4][4];
#pragma unroll
    for (int i = 0; i < 4; ++i)
#pragma unroll
        for (int j = 0; j < 4; ++j) acc[i][j] = 0.f;

    for (int kc = 0; kc < K; kc += 32) {
#pragma unroll
        for (int rr = 0; rr < 2; ++rr) {
            const int m = mr + rr * 32;
            f32x4 xv = *(const f32x4*)(X + (size_t)(m0 + m) * K + kc + kq * 4);
            f32x4 wv = *(const f32x4*)(Wt + (size_t)(n0 + m) * K + kc + kq * 4);
#pragma unroll
            for (int j = 0; j < 4; ++j) { Xs[kq*4 + j][m] = xv[j]; Ws[kq*4 + j][m] = wv[j]; }
        }
        __syncthreads();
#pragma unroll
        for (int k = 0; k < 32; ++k) {
            f32x4 a = *(const f32x4*)&Xs[k][ty * 4];
            f32x4 b = *(const f32x4*)&Ws[k][tx * 4];
#pragma unroll
            for (int i = 0; i < 4; ++i)
#pragma unroll
                for (int j = 0; j < 4; ++j)
                    acc[i][j] = __builtin_fmaf(a[i], b[j], acc[i][j]);
        }
        __syncthreads();
    }
    f32x4 bv = *(const f32x4*)(bias + n0 + tx * 4);
#pragma unroll
    for (int i = 0; i < 4; ++i) {
        f32x4 o;
#pragma unroll
        for (int j = 0; j < 4; ++j) o[j] = acc[i][j] + bv[j];
        *(f32x4*)(Out + (size_t)(m0 + ty * 4 + i) * N + n0 + tx * 4) = o;
    }
}

// ---------------------------------------------------------------------------
// Recurrent scan, register-only h.  1024 blocks x 64 threads; each wave owns
// 16 cells (cell = cellbase + (lane&15)) for all 512 steps; 1 wave/SIMD.
//
// MFMA 16x16x32 bf16 layouts, lane l, c15=l&15, g4=l>>4:
//   A: lane elems 0-3 hold A[c15][kbase + 4*g4 + e], elems 4-7: +16
//   B: lane elems 0-3 hold B[kbase + 4*g4 + e][c15], elems 4-7: +16
//   D: lane reg e holds D[4*g4 + e][c15]
// 16x16x16 (_1k): same with single 4-elem K group (k = 4*g4 + e).
//
// acc[nt] (nt=0..15): lane (g4,c15) elem e = PRE-SCALED gate nt*16+4g4+e of
// cell c15; type=nt>>2 in {i,f,g,o}; scale -log2e for i/f/o, +2log2e for g.
// ---------------------------------------------------------------------------
__global__ __launch_bounds__(64, 1) void lstm_scan(
    const float* __restrict__ x2n,   // [512][16384]
    const float* __restrict__ W_hh,  // [256][64]
    const float* __restrict__ w_ih,  // [256]
    const float* __restrict__ b_ih,  // [256]
    const float* __restrict__ b_hh,  // [256]
    const float* __restrict__ wg,    // [64]
    const float* __restrict__ bg,    // [1]
    float* __restrict__ ON)          // [512][16384]
{
    const int lane = threadIdx.x & 63;
    const int c15 = lane & 15, g4 = lane >> 4;
    const int cellbase = blockIdx.x * 16;

    const float L2E = 1.4426950408889634f;   // log2(e)

    // W_hh A-fragments (K=32 pairs) + ext-slice fragments (K=16), PRE-SCALED.
    s16x8 afw8[2][16];
    s16x4 afx4[16];
#pragma unroll
    for (int nt = 0; nt < 16; ++nt) {
        const float sc = ((nt >> 2) == 2) ? (2.f * L2E) : (-L2E);
        const float* wrow = W_hh + (size_t)(nt * 16 + c15) * 64;
#pragma unroll
        for (int kp = 0; kp < 2; ++kp) {
            s16x8 v;
#pragma unroll
            for (int half = 0; half < 2; ++half) {
                f32x4 w = *(const f32x4*)(wrow + (kp * 2 + half) * 16 + g4 * 4);
#pragma unroll
                for (int e = 0; e < 4; ++e) v[half * 4 + e] = bf16r(w[e] * sc);
            }
            afw8[kp][nt] = v;
        }
        // Ext slice A row (K=16), paired with B-ext (xh, xl, xh, 1 | 1, 0...).
        const int g = nt * 16 + c15;
        const float wi = w_ih[g] * sc;
        const float bs = (b_ih[g] + b_hh[g]) * sc;
        const short wh = bf16r(wi);
        const short wl = bf16r(wi - bf2f(wh));
        const short bh_ = bf16r(bs);
        const short bl_ = bf16r(bs - bf2f(bh_));
        s16x4 v = (s16x4){0, 0, 0, 0};
        if (g4 == 0) { v[0] = wh; v[1] = wh; v[2] = wl; v[3] = bh_; }
        else if (g4 == 1) { v[0] = bl_; }
        afx4[nt] = v;
    }

    // g-MFMA A-fragments: A row 0 = wg (pre-rounded bf16), rows 1-15 = 0.
    // afg8[kp] covers K = 32*kp .. 32*kp+31.
    s16x8 afg8[2];
#pragma unroll
    for (int kp = 0; kp < 2; ++kp) {
        s16x8 v = (s16x8){0, 0, 0, 0, 0, 0, 0, 0};
        if (c15 == 0) {
            const f32x4 w0 = *(const f32x4*)(wg + kp * 32 + g4 * 4);
            const f32x4 w1 = *(const f32x4*)(wg + kp * 32 + 16 + g4 * 4);
#pragma unroll
            for (int e = 0; e < 4; ++e) { v[e] = bf16r(w0[e]); v[4 + e] = bf16r(w1[e]); }
        }
        afg8[kp] = v;
    }

    // Pin weight fragments (one-time; R7-champion recipe).
#pragma unroll
    for (int nt = 0; nt < 16; ++nt) {
        asm volatile("" : "+v"(afw8[0][nt]));
        asm volatile("" : "+v"(afw8[1][nt]));
        asm volatile("" : "+v"(afx4[nt]));
    }
    asm volatile("" : "+v"(afg8[0]));
    asm volatile("" : "+v"(afg8[1]));

    const float bg0 = bg[0];
    const short one_bf = (short)0x3F80;

    f32x4 cst[4];
#pragma unroll
    for (int q = 0; q < 4; ++q) cst[q] = (f32x4){0.f, 0.f, 0.f, 0.f};
    s16x8 bh01 = (s16x8){0, 0, 0, 0, 0, 0, 0, 0};   // h k=0..31  B-fragment
    s16x8 bh23 = (s16x8){0, 0, 0, 0, 0, 0, 0, 0};   // h k=32..63 B-fragment

    // g pipeline: gmf = g-MFMA result of the PREVIOUS step (read 1 step
    // late); gq = g value extracted one further step back (= g_{t-2} at use).
    f32x4 gmf = (f32x4){0.f, 0.f, 0.f, 0.f};
    float gq = 0.f;
    float sp0 = 0.f;

    const size_t cellidx = (size_t)cellbase + c15;
    float xs = x2n[cellidx];          // x for (t=0, cell c15), prefetched

    for (int t = 0; t < 512; ++t) {
        // gain for this step (= g_{t-2}) from the 2-step-old extraction;
        // then advance the extraction (reads gmf issued a full step ago).
        const float gain_f = gq + bg0;
        gq = gmf[0];                  // valid in lanes g4==0 (D row 0)

        // B extension fragment from x (hi/lo bf16 split), K=16
        const float xs_cur = xs;
        const short xh = bf16r(xs_cur);
        const short xl = bf16r(xs_cur - bf2f(xh));
        s16x4 bx4 = (s16x4){0, 0, 0, 0};
        if (g4 == 0) { bx4[0] = xh; bx4[1] = xl; bx4[2] = xh; bx4[3] = one_bf; }
        else if (g4 == 1) { bx4[0] = one_bf; }
        xs = x2n[(size_t)((t + 1) & 511) * 16384 + cellidx]; // branchless prefetch

        // gates^T (pre-scaled): ext K=16 slice + two K=32 slices of W_hh@h^T
        f32x4 acc[16];
        const f32x4 zero4 = (f32x4){0.f, 0.f, 0.f, 0.f};
#if HAVE_MFMA16
#pragma unroll
        for (int nt = 0; nt < 16; ++nt) acc[nt] = mfma16(afx4[nt], bx4, zero4);
#else
        {
            const s16x4 z4 = (s16x4){0, 0, 0, 0};
            const s16x8 bx8 = cat8(bx4, z4);
#pragma unroll
            for (int nt = 0; nt < 16; ++nt)
                acc[nt] = mfma32(cat8(afx4[nt], z4), bx8, zero4);
        }
#endif
#pragma unroll
        for (int nt = 0; nt < 16; ++nt) acc[nt] = mfma32(afw8[0][nt], bh01, acc[nt]);
#pragma unroll
        for (int nt = 0; nt < 16; ++nt) acc[nt] = mfma32(afw8[1][nt], bh23, acc[nt]);

        // ---- merged nonlinearities, rcps paired across (qa,qb) ----
        f32x4 hvf[4];
#pragma unroll
        for (int qp = 0; qp < 2; ++qp) {
            const int qa = 2 * qp, qb = qa + 1;
            f32x4 cna, cnb, hna, hnb;
#pragma unroll
            for (int e = 0; e < 4; ++e) {
                const float ufa = __builtin_amdgcn_exp2f(acc[qa + 4][e]);
                const float ufb = __builtin_amdgcn_exp2f(acc[qb + 4][e]);
                const float dfa = 1.f + ufa, dfb = 1.f + ufb;
                const float rf = __builtin_amdgcn_rcpf(dfa * dfb);
                const float sfa = rf * dfb, sfb = rf * dfa;

                const float uia = __builtin_amdgcn_exp2f(acc[qa][e]);
                const float uib = __builtin_amdgcn_exp2f(acc[qb][e]);
                const float vga = __builtin_amdgcn_exp2f(acc[qa + 8][e]);
                const float vgb = __builtin_amdgcn_exp2f(acc[qb + 8][e]);
                const float Da = (1.f + uia) * (1.f + vga);
                const float Db = (1.f + uib) * (1.f + vgb);
                const float rp = __builtin_amdgcn_rcpf(Da * Db);
                const float pa = (vga - 1.f) * (Db * rp);
                const float pb = (vgb - 1.f) * (Da * rp);

                const float ca = __builtin_fmaf(sfa, cst[qa][e], pa);
                const float cb = __builtin_fmaf(sfb, cst[qb][e], pb);
                cna[e] = ca; cnb[e] = cb;

                const float uoa = __builtin_amdgcn_exp2f(acc[qa + 12][e]);
                const float uob = __builtin_amdgcn_exp2f(acc[qb + 12][e]);
                const float vca = __builtin_amdgcn_exp2f(fminf(2.8853900817779268f * ca, 43.f));
                const float vcb = __builtin_amdgcn_exp2f(fminf(2.8853900817779268f * cb, 43.f));
                const float Ea = (1.f + uoa) * (1.f + vca);
                const float Eb = (1.f + uob) * (1.f + vcb);
                const float rh = __builtin_amdgcn_rcpf(Ea * Eb);
                hna[e] = (vca - 1.f) * (Eb * rh);
                hnb[e] = (vcb - 1.f) * (Ea * rh);
            }
            cst[qa] = cna; cst[qb] = cnb;
            hvf[qa] = hna; hvf[qb] = hnb;
        }

        // next-step B fragments via packed cvt (RNE), directly as K=32 pairs
        bh01 = __builtin_bit_cast(s16x8,
                   (u32x4){pkbf(hvf[0][0], hvf[0][1]), pkbf(hvf[0][2], hvf[0][3]),
                           pkbf(hvf[1][0], hvf[1][1]), pkbf(hvf[1][2], hvf[1][3])});
        bh23 = __builtin_bit_cast(s16x8,
                   (u32x4){pkbf(hvf[2][0], hvf[2][1]), pkbf(hvf[2][2], hvf[2][3]),
                           pkbf(hvf[3][0], hvf[3][1]), pkbf(hvf[3][2], hvf[3][3])});

        // g_t = wg . h_t via 2 MFMAs (D row 0 -> reg0 of g4==0 lanes);
        // result is consumed 2 steps later, so latency is fully hidden.
        gmf = mfma32(afg8[1], bh23, mfma32(afg8[0], bh01, zero4));

        // out[t,cell] = gain * softplus(x-1); gain = g_t, 1, g_{t-2}
        const float x1 = xs_cur - 1.f;
        const float sp = fmaxf(x1, 0.f) +
            0.6931471805599453f * __builtin_amdgcn_logf(
                1.f + __builtin_amdgcn_exp2f(-1.4426950408889634f * fabsf(x1)));
        if (t >= 2) {
            if (g4 == 0) {
                ON[(size_t)t * 16384 + cellidx] = gain_f * sp;
                if (t == 2) ON[cellidx] = gain_f * sp0;        // gain_0 = g_0
            }
        } else if (t == 1) {
            if (g4 == 0) ON[(size_t)16384 + cellidx] = sp;     // gain = 1
        } else {
            sp0 = sp;                                // ON[0] deferred to t==2
        }
    }
}

extern "C" void kernel_launch(void* const* d_in, const int* in_sizes, int n_in,
                              void* d_out, int out_size, void* d_ws, size_t ws_size,
                              hipStream_t stream)
{
    const float* input = (const float*)d_in[0];   // [512][64][128]
    const float* W2n   = (const float*)d_in[1];   // [256][128]
    const float* b2n   = (const float*)d_in[2];   // [256]
    const float* W_ih  = (const float*)d_in[3];   // [256] (4H x 1)
    const float* W_hh  = (const float*)d_in[4];   // [256][64]
    const float* b_ih  = (const float*)d_in[5];   // [256]
    const float* b_hh  = (const float*)d_in[6];   // [256]
    const float* Wg    = (const float*)d_in[7];   // [64]  (1 x H)
    const float* bg    = (const float*)d_in[8];   // [1]
    const float* Wout  = (const float*)d_in[9];   // [64][256]
    const float* bout  = (const float*)d_in[10];  // [64]

    float* x2n = (float*)d_ws;                          // 512*16384 f32 = 32MB
    float* ON  = x2n + (size_t)512 * 16384;             // another 32MB

    // Stage 1: x2n = input @ W2n^T + b2n   (M=32768, N=256, K=128)
    gemm_xwT<<<dim3(512, 4), 256, 0, stream>>>(input, W2n, b2n, x2n, 256, 128);

    // Stage 2: recurrent scan -> ON  (1024 waves = 1/SIMD on all 256 CUs)
    lstm_scan<<<1024, 64, 0, stream>>>(x2n, W_hh, W_ih, b_ih, b_hh, Wg, bg, ON);

    // Stage 3: out = ON @ Wout^T + bout    (M=32768, N=64, K=256)
    gemm_xwT<<<dim3(512, 1), 256, 0, stream>>>(ON, Wout, bout, (float*)d_out, 64, 256);
}